// Round 1
// baseline (366.350 us; speedup 1.0000x reference)
//
#include <hip/hip_runtime.h>
#include <hip/hip_bf16.h>
#include <math.h>

typedef __bf16 bf16;
typedef bf16 bf16x8 __attribute__((ext_vector_type(8)));
typedef float f32x4 __attribute__((ext_vector_type(4)));
typedef unsigned short ushort_t;

#define N_NODES 100000
#define N_EDGES 640000
#define DD 128
#define MAXDEG 64

__device__ __forceinline__ float gelu_f(float x) {
    return 0.5f * x * (1.0f + erff(x * 0.70710678118654752440f));
}

__device__ __forceinline__ ushort_t bf16_bits(float x) {
    bf16 h = (bf16)x;
    return __builtin_bit_cast(ushort_t, h);
}

// ---------------- K1: h0 = nf @ W1 + b1 (fp32 out) + stats partials ----------
__global__ __launch_bounds__(256) void k1_gemm1(
    const float* __restrict__ nf, const float* __restrict__ W1,
    const float* __restrict__ b1, float* __restrict__ h0,
    float* __restrict__ psum, float* __restrict__ psq, int nblocks)
{
    __shared__ bf16 Ash[16 * 136];
    __shared__ float red[256];
    const int tid = threadIdx.x;
    const int lane = tid & 63;
    const int w = tid >> 6;
    const int l15 = lane & 15, l4 = lane >> 4;

    // B fragments in registers: 4 k-steps x 2 col tiles (wave w owns cols w*32..w*32+31)
    bf16x8 bfrag[4][2];
    #pragma unroll
    for (int s = 0; s < 4; ++s)
        #pragma unroll
        for (int t = 0; t < 2; ++t) {
            int n = w * 32 + t * 16 + l15;
            #pragma unroll
            for (int j = 0; j < 8; ++j) {
                int k = s * 32 + l4 * 8 + j;
                bfrag[s][t][j] = (bf16)W1[k * DD + n];
            }
        }
    float bias[2];
    bias[0] = b1[w * 32 + l15];
    bias[1] = b1[w * 32 + 16 + l15];

    float lsum = 0.f, lsq = 0.f;
    const int srow = tid >> 4, skc = (tid & 15) * 8;

    for (int tile = blockIdx.x; tile < N_NODES / 16; tile += nblocks) {
        const int rbase = tile * 16;
        // stage A tile (16 rows x 128) fp32 -> bf16 LDS
        {
            const float4* p = (const float4*)&nf[(size_t)(rbase + srow) * DD + skc];
            float4 a = p[0], b = p[1];
            bf16* dst = &Ash[srow * 136 + skc];
            dst[0] = (bf16)a.x; dst[1] = (bf16)a.y; dst[2] = (bf16)a.z; dst[3] = (bf16)a.w;
            dst[4] = (bf16)b.x; dst[5] = (bf16)b.y; dst[6] = (bf16)b.z; dst[7] = (bf16)b.w;
        }
        __syncthreads();
        f32x4 acc[2] = {{0.f,0.f,0.f,0.f},{0.f,0.f,0.f,0.f}};
        #pragma unroll
        for (int s = 0; s < 4; ++s) {
            bf16x8 a = *(const bf16x8*)&Ash[l15 * 136 + s * 32 + l4 * 8];
            acc[0] = __builtin_amdgcn_mfma_f32_16x16x32_bf16(a, bfrag[s][0], acc[0], 0, 0, 0);
            acc[1] = __builtin_amdgcn_mfma_f32_16x16x32_bf16(a, bfrag[s][1], acc[1], 0, 0, 0);
        }
        __syncthreads();
        #pragma unroll
        for (int t = 0; t < 2; ++t) {
            int n = w * 32 + t * 16 + l15;
            #pragma unroll
            for (int j = 0; j < 4; ++j) {
                float v = acc[t][j] + bias[t];
                int r = rbase + l4 * 4 + j;
                h0[(size_t)r * DD + n] = v;
                lsum += v; lsq += v * v;
            }
        }
    }
    // block reduction of stats
    red[tid] = lsum; __syncthreads();
    for (int s = 128; s > 0; s >>= 1) { if (tid < s) red[tid] += red[tid + s]; __syncthreads(); }
    if (tid == 0) psum[blockIdx.x] = red[0];
    __syncthreads();
    red[tid] = lsq; __syncthreads();
    for (int s = 128; s > 0; s >>= 1) { if (tid < s) red[tid] += red[tid + s]; __syncthreads(); }
    if (tid == 0) psq[blockIdx.x] = red[0];
}

// ---------------- reduce partials -> mu, rsigma ------------------------------
__global__ void k_reduce(const float* __restrict__ psum, const float* __restrict__ psq,
                         int nb, double cntd, float* __restrict__ scal)
{
    __shared__ double rs_[256], rq_[256];
    int tid = threadIdx.x;
    double s = 0.0, q = 0.0;
    for (int i = tid; i < nb; i += 256) { s += psum[i]; q += psq[i]; }
    rs_[tid] = s; rq_[tid] = q; __syncthreads();
    for (int st = 128; st > 0; st >>= 1) {
        if (tid < st) { rs_[tid] += rs_[tid + st]; rq_[tid] += rq_[tid + st]; }
        __syncthreads();
    }
    if (tid == 0) {
        double mu = rs_[0] / cntd;
        double var = rq_[0] / cntd - mu * mu;
        scal[0] = (float)mu;
        scal[1] = (float)(1.0 / sqrt(var + 1e-5));
    }
}

// ---------------- K3: hg = bf16(gelu((h0-mu)*rs)) ----------------------------
__global__ __launch_bounds__(256) void k3_act(
    const float* __restrict__ h0, const float* __restrict__ scal,
    ushort_t* __restrict__ hg)
{
    const float mu = scal[0], rs = scal[1];
    size_t i = (size_t)(blockIdx.x * 256 + threadIdx.x) * 8;
    const float4* p = (const float4*)(h0 + i);
    float4 a = p[0], b = p[1];
    float vals[8] = {a.x, a.y, a.z, a.w, b.x, b.y, b.z, b.w};
    ushort_t o[8];
    #pragma unroll
    for (int j = 0; j < 8; ++j)
        o[j] = bf16_bits(gelu_f((vals[j] - mu) * rs));
    *(uint4*)(hg + i) = *(const uint4*)o;
}

// ---------------- K4: e0 = [ef | hg[src]] @ W2 + b2 (bf16 out) + stats -------
__global__ __launch_bounds__(256) void k4_gemm2(
    const float* __restrict__ ef, const ushort_t* __restrict__ hg,
    const int* __restrict__ eidx, const float* __restrict__ W2,
    const float* __restrict__ b2, ushort_t* __restrict__ e0,
    float* __restrict__ psum, float* __restrict__ psq, int nblocks)
{
    __shared__ bf16 Ash[16 * 264];
    __shared__ float red[256];
    const int tid = threadIdx.x;
    const int lane = tid & 63;
    const int w = tid >> 6;
    const int l15 = lane & 15, l4 = lane >> 4;

    // B fragments: 8 k-steps x 2 col tiles
    bf16x8 bfrag[8][2];
    #pragma unroll
    for (int s = 0; s < 8; ++s)
        #pragma unroll
        for (int t = 0; t < 2; ++t) {
            int n = w * 32 + t * 16 + l15;
            #pragma unroll
            for (int j = 0; j < 8; ++j)
                bfrag[s][t][j] = (bf16)W2[(s * 32 + l4 * 8 + j) * DD + n];
        }
    float bias[2];
    bias[0] = b2[w * 32 + l15];
    bias[1] = b2[w * 32 + 16 + l15];

    float lsum = 0.f, lsq = 0.f;
    const int srow = tid >> 4, skc = (tid & 15) * 8;

    for (int tile = blockIdx.x; tile < N_EDGES / 16; tile += nblocks) {
        const int ebase = tile * 16;
        // stage A tile: [16 rows][256] bf16; first 128 = ef (cvt), last 128 = gathered hg
        {
            const float4* p = (const float4*)&ef[(size_t)(ebase + srow) * DD + skc];
            float4 a = p[0], b = p[1];
            bf16* dst = &Ash[srow * 264 + skc];
            dst[0] = (bf16)a.x; dst[1] = (bf16)a.y; dst[2] = (bf16)a.z; dst[3] = (bf16)a.w;
            dst[4] = (bf16)b.x; dst[5] = (bf16)b.y; dst[6] = (bf16)b.z; dst[7] = (bf16)b.w;
            int src = eidx[(size_t)(ebase + srow) * 2];
            uint4 v = *(const uint4*)&hg[(size_t)src * DD + skc];
            *(uint4*)&Ash[srow * 264 + 128 + skc] = v;
        }
        __syncthreads();
        f32x4 acc[2] = {{0.f,0.f,0.f,0.f},{0.f,0.f,0.f,0.f}};
        #pragma unroll
        for (int s = 0; s < 8; ++s) {
            bf16x8 a = *(const bf16x8*)&Ash[l15 * 264 + s * 32 + l4 * 8];
            acc[0] = __builtin_amdgcn_mfma_f32_16x16x32_bf16(a, bfrag[s][0], acc[0], 0, 0, 0);
            acc[1] = __builtin_amdgcn_mfma_f32_16x16x32_bf16(a, bfrag[s][1], acc[1], 0, 0, 0);
        }
        __syncthreads();
        #pragma unroll
        for (int t = 0; t < 2; ++t) {
            int n = w * 32 + t * 16 + l15;
            #pragma unroll
            for (int j = 0; j < 4; ++j) {
                float v = acc[t][j] + bias[t];
                lsum += v; lsq += v * v;
                int r = ebase + l4 * 4 + j;
                e0[(size_t)r * DD + n] = bf16_bits(v);
            }
        }
    }
    red[tid] = lsum; __syncthreads();
    for (int s = 128; s > 0; s >>= 1) { if (tid < s) red[tid] += red[tid + s]; __syncthreads(); }
    if (tid == 0) psum[blockIdx.x] = red[0];
    __syncthreads();
    red[tid] = lsq; __syncthreads();
    for (int s = 128; s > 0; s >>= 1) { if (tid < s) red[tid] += red[tid + s]; __syncthreads(); }
    if (tid == 0) psq[blockIdx.x] = red[0];
}

// ---------------- K7: bucket edges by dst ------------------------------------
__global__ __launch_bounds__(256) void k7_fill(
    const int* __restrict__ eidx, int* __restrict__ cnt, int* __restrict__ slot)
{
    int e = blockIdx.x * 256 + threadIdx.x;
    if (e >= N_EDGES) return;
    int dst = eidx[(size_t)e * 2 + 1];
    int pos = atomicAdd(&cnt[dst], 1);
    if (pos < MAXDEG) slot[dst * MAXDEG + pos] = e;
}

// ---------------- K8: per-node gather + norm + gelu + mean -------------------
__global__ __launch_bounds__(256) void k8_gather(
    const ushort_t* __restrict__ e0, const int* __restrict__ slot,
    const int* __restrict__ cnt, const float* __restrict__ scal,
    float* __restrict__ out)
{
    const float mu = scal[0], rs = scal[1];
    int warp = (int)((blockIdx.x * 256 + threadIdx.x) >> 6);
    int lane = threadIdx.x & 63;
    if (warp >= N_NODES) return;
    int c = cnt[warp];
    int m = min(c, MAXDEG);
    float a0 = 0.f, a1 = 0.f;
    for (int j = 0; j < m; ++j) {
        int e = slot[warp * MAXDEG + j];
        unsigned u = *(const unsigned*)&e0[(size_t)e * DD + lane * 2];
        float x0 = __uint_as_float(u << 16);
        float x1 = __uint_as_float(u & 0xffff0000u);
        a0 += gelu_f((x0 - mu) * rs);
        a1 += gelu_f((x1 - mu) * rs);
    }
    float inv = c > 0 ? 1.0f / (float)c : 0.f;
    out[(size_t)warp * DD + lane * 2] = a0 * inv;
    out[(size_t)warp * DD + lane * 2 + 1] = a1 * inv;
}

// ---------------- launch -----------------------------------------------------
extern "C" void kernel_launch(void* const* d_in, const int* in_sizes, int n_in,
                              void* d_out, int out_size, void* d_ws, size_t ws_size,
                              hipStream_t stream) {
    const float* ef  = (const float*)d_in[0];
    const float* nf  = (const float*)d_in[1];
    const int*   eix = (const int*)d_in[2];
    const float* W1  = (const float*)d_in[3];
    const float* b1  = (const float*)d_in[4];
    const float* W2  = (const float*)d_in[5];
    const float* b2  = (const float*)d_in[6];
    float* out = (float*)d_out;
    char* ws = (char*)d_ws;

    // workspace layout (bytes, 256-aligned)
    float*    h0   = (float*)(ws + 0);            // 12.8M fp32  = 51,200,000
    ushort_t* hg   = (ushort_t*)(ws + 51200000);  // 12.8M bf16  = 25,600,000
    ushort_t* e0   = (ushort_t*)(ws + 76800000);  // 81.92M bf16 = 163,840,000
    int*      cnt  = (int*)(ws + 240640000);      // 100000 int
    int*      slot = (int*)(ws + 241040128);      // 6.4M int    = 25,600,000
    float*    p1s  = (float*)(ws + 266640128);    // 1024 f
    float*    p1q  = p1s + 1024;
    float*    p2s  = (float*)(ws + 266648320);    // 2048 f
    float*    p2q  = p2s + 2048;
    float*    s1   = (float*)(ws + 266664704);    // mu1, rs1
    float*    s2   = (float*)(ws + 266664960);    // mu2, rs2

    hipMemsetAsync(cnt, 0, N_NODES * sizeof(int), stream);
    k1_gemm1<<<1024, 256, 0, stream>>>(nf, W1, b1, h0, p1s, p1q, 1024);
    k_reduce<<<1, 256, 0, stream>>>(p1s, p1q, 1024, (double)N_NODES * DD, s1);
    k3_act<<<6250, 256, 0, stream>>>(h0, s1, hg);
    k4_gemm2<<<2048, 256, 0, stream>>>(ef, hg, eix, W2, b2, e0, p2s, p2q, 2048);
    k_reduce<<<1, 256, 0, stream>>>(p2s, p2q, 2048, (double)N_EDGES * DD, s2);
    k7_fill<<<2500, 256, 0, stream>>>(eix, cnt, slot);
    k8_gather<<<25000, 256, 0, stream>>>(e0, slot, cnt, s2, out);
}

// Round 2
// 349.961 us; speedup vs baseline: 1.0468x; 1.0468x over previous
//
#include <hip/hip_runtime.h>
#include <hip/hip_bf16.h>
#include <math.h>

typedef __bf16 bf16;
typedef bf16 bf16x8 __attribute__((ext_vector_type(8)));
typedef float f32x4 __attribute__((ext_vector_type(4)));
typedef unsigned short ushort_t;

#define N_NODES 100000
#define N_EDGES 640000
#define DD 128
#define MAXDEG 64

__device__ __forceinline__ float gelu_f(float x) {
    return 0.5f * x * (1.0f + erff(x * 0.70710678118654752440f));
}

__device__ __forceinline__ ushort_t bf16_bits(float x) {
    bf16 h = (bf16)x;
    return __builtin_bit_cast(ushort_t, h);
}

__device__ __forceinline__ float bits_to_f(ushort_t u) {
    return __uint_as_float(((unsigned)u) << 16);
}

// ---------------- K1: hpre = bf16(nf @ W1 + b1) + fp32 stats partials --------
__global__ __launch_bounds__(256) void k1_gemm1(
    const float* __restrict__ nf, const float* __restrict__ W1,
    const float* __restrict__ b1, ushort_t* __restrict__ hpre,
    float* __restrict__ psum, float* __restrict__ psq, int nblocks)
{
    __shared__ bf16 Ash[16 * 136];
    __shared__ float red[256];
    const int tid = threadIdx.x;
    const int lane = tid & 63;
    const int w = tid >> 6;
    const int l15 = lane & 15, l4 = lane >> 4;

    bf16x8 bfrag[4][2];
    #pragma unroll
    for (int s = 0; s < 4; ++s)
        #pragma unroll
        for (int t = 0; t < 2; ++t) {
            int n = w * 32 + t * 16 + l15;
            #pragma unroll
            for (int j = 0; j < 8; ++j)
                bfrag[s][t][j] = (bf16)W1[(s * 32 + l4 * 8 + j) * DD + n];
        }
    float bias[2];
    bias[0] = b1[w * 32 + l15];
    bias[1] = b1[w * 32 + 16 + l15];

    float lsum = 0.f, lsq = 0.f;
    const int srow = tid >> 4, skc = (tid & 15) * 8;

    for (int tile = blockIdx.x; tile < N_NODES / 16; tile += nblocks) {
        const int rbase = tile * 16;
        {
            const float4* p = (const float4*)&nf[(size_t)(rbase + srow) * DD + skc];
            float4 a = p[0], b = p[1];
            ushort_t o[8] = {bf16_bits(a.x), bf16_bits(a.y), bf16_bits(a.z), bf16_bits(a.w),
                             bf16_bits(b.x), bf16_bits(b.y), bf16_bits(b.z), bf16_bits(b.w)};
            *(uint4*)&Ash[srow * 136 + skc] = *(const uint4*)o;
        }
        __syncthreads();
        f32x4 acc[2] = {{0.f,0.f,0.f,0.f},{0.f,0.f,0.f,0.f}};
        #pragma unroll
        for (int s = 0; s < 4; ++s) {
            bf16x8 a = *(const bf16x8*)&Ash[l15 * 136 + s * 32 + l4 * 8];
            acc[0] = __builtin_amdgcn_mfma_f32_16x16x32_bf16(a, bfrag[s][0], acc[0], 0, 0, 0);
            acc[1] = __builtin_amdgcn_mfma_f32_16x16x32_bf16(a, bfrag[s][1], acc[1], 0, 0, 0);
        }
        __syncthreads();
        #pragma unroll
        for (int t = 0; t < 2; ++t) {
            int n = w * 32 + t * 16 + l15;
            #pragma unroll
            for (int j = 0; j < 4; ++j) {
                float v = acc[t][j] + bias[t];
                int r = rbase + l4 * 4 + j;
                hpre[(size_t)r * DD + n] = bf16_bits(v);
                lsum += v; lsq += v * v;
            }
        }
    }
    red[tid] = lsum; __syncthreads();
    for (int s = 128; s > 0; s >>= 1) { if (tid < s) red[tid] += red[tid + s]; __syncthreads(); }
    if (tid == 0) psum[blockIdx.x] = red[0];
    __syncthreads();
    red[tid] = lsq; __syncthreads();
    for (int s = 128; s > 0; s >>= 1) { if (tid < s) red[tid] += red[tid + s]; __syncthreads(); }
    if (tid == 0) psq[blockIdx.x] = red[0];
}

// ---------------- reduce partials -> mu, rsigma ------------------------------
__global__ void k_reduce(const float* __restrict__ psum, const float* __restrict__ psq,
                         int nb, double cntd, float* __restrict__ scal)
{
    __shared__ double rs_[256], rq_[256];
    int tid = threadIdx.x;
    double s = 0.0, q = 0.0;
    for (int i = tid; i < nb; i += 256) { s += psum[i]; q += psq[i]; }
    rs_[tid] = s; rq_[tid] = q; __syncthreads();
    for (int st = 128; st > 0; st >>= 1) {
        if (tid < st) { rs_[tid] += rs_[tid + st]; rq_[tid] += rq_[tid + st]; }
        __syncthreads();
    }
    if (tid == 0) {
        double mu = rs_[0] / cntd;
        double var = rq_[0] / cntd - mu * mu;
        scal[0] = (float)mu;
        scal[1] = (float)(1.0 / sqrt(var + 1e-5));
    }
}

// ---------------- K3: hg = bf16(gelu((hpre-mu)*rs)) --------------------------
__global__ __launch_bounds__(256) void k3_act(
    const ushort_t* __restrict__ hpre, const float* __restrict__ scal,
    ushort_t* __restrict__ hg)
{
    const float mu = scal[0], rs = scal[1];
    size_t i = (size_t)(blockIdx.x * 256 + threadIdx.x) * 8;
    uint4 v = *(const uint4*)(hpre + i);
    const ushort_t* in = (const ushort_t*)&v;
    ushort_t o[8];
    #pragma unroll
    for (int j = 0; j < 8; ++j)
        o[j] = bf16_bits(gelu_f((bits_to_f(in[j]) - mu) * rs));
    *(uint4*)(hg + i) = *(const uint4*)o;
}

// ---------------- K4: e0 = [ef | hg[src]] @ W2 + b2 (bf16) + stats -----------
// 64-row tiles: 4x barrier amortization vs R1.
__global__ __launch_bounds__(256) void k4_gemm2(
    const float* __restrict__ ef, const ushort_t* __restrict__ hg,
    const int* __restrict__ eidx, const float* __restrict__ W2,
    const float* __restrict__ b2, ushort_t* __restrict__ e0,
    float* __restrict__ psum, float* __restrict__ psq, int nblocks)
{
    __shared__ bf16 Ash[64 * 264];   // 33792 B, stride 528 B (2-way-free banks)
    __shared__ float red[256];
    const int tid = threadIdx.x;
    const int lane = tid & 63;
    const int w = tid >> 6;
    const int l15 = lane & 15, l4 = lane >> 4;

    bf16x8 bfrag[8][2];
    #pragma unroll
    for (int s = 0; s < 8; ++s)
        #pragma unroll
        for (int t = 0; t < 2; ++t) {
            int n = w * 32 + t * 16 + l15;
            #pragma unroll
            for (int j = 0; j < 8; ++j)
                bfrag[s][t][j] = (bf16)W2[(s * 32 + l4 * 8 + j) * DD + n];
        }
    float bias[2];
    bias[0] = b2[w * 32 + l15];
    bias[1] = b2[w * 32 + 16 + l15];

    float lsum = 0.f, lsq = 0.f;
    const int srow = tid >> 2;       // 0..63
    const int q = tid & 3;           // 32-col quarter

    for (int tile = blockIdx.x; tile < N_EDGES / 64; tile += nblocks) {
        const int ebase = tile * 64;
        // stage ef half: row srow, cols q*32..q*32+31 (fp32 -> bf16, packed uint4)
        {
            const float4* p = (const float4*)&ef[(size_t)(ebase + srow) * DD + q * 32];
            #pragma unroll
            for (int u = 0; u < 4; ++u) {
                float4 a = p[2 * u], b = p[2 * u + 1];
                ushort_t o[8] = {bf16_bits(a.x), bf16_bits(a.y), bf16_bits(a.z), bf16_bits(a.w),
                                 bf16_bits(b.x), bf16_bits(b.y), bf16_bits(b.z), bf16_bits(b.w)};
                *(uint4*)&Ash[srow * 264 + q * 32 + u * 8] = *(const uint4*)o;
            }
            // stage gathered hg half (already bf16)
            int src = eidx[(size_t)(ebase + srow) * 2];
            const uint4* hp = (const uint4*)&hg[(size_t)src * DD + q * 32];
            uint4* hd = (uint4*)&Ash[srow * 264 + 128 + q * 32];
            #pragma unroll
            for (int u = 0; u < 4; ++u) hd[u] = hp[u];
        }
        __syncthreads();
        f32x4 acc[4][2];
        #pragma unroll
        for (int r = 0; r < 4; ++r)
            #pragma unroll
            for (int t = 0; t < 2; ++t)
                acc[r][t] = (f32x4){0.f, 0.f, 0.f, 0.f};
        #pragma unroll
        for (int s = 0; s < 8; ++s) {
            #pragma unroll
            for (int r = 0; r < 4; ++r) {
                bf16x8 a = *(const bf16x8*)&Ash[(r * 16 + l15) * 264 + s * 32 + l4 * 8];
                acc[r][0] = __builtin_amdgcn_mfma_f32_16x16x32_bf16(a, bfrag[s][0], acc[r][0], 0, 0, 0);
                acc[r][1] = __builtin_amdgcn_mfma_f32_16x16x32_bf16(a, bfrag[s][1], acc[r][1], 0, 0, 0);
            }
        }
        __syncthreads();
        #pragma unroll
        for (int r = 0; r < 4; ++r)
            #pragma unroll
            for (int t = 0; t < 2; ++t) {
                int n = w * 32 + t * 16 + l15;
                #pragma unroll
                for (int j = 0; j < 4; ++j) {
                    float v = acc[r][t][j] + bias[t];
                    lsum += v; lsq += v * v;
                    int rr = ebase + r * 16 + l4 * 4 + j;
                    e0[(size_t)rr * DD + n] = bf16_bits(v);
                }
            }
    }
    red[tid] = lsum; __syncthreads();
    for (int s = 128; s > 0; s >>= 1) { if (tid < s) red[tid] += red[tid + s]; __syncthreads(); }
    if (tid == 0) psum[blockIdx.x] = red[0];
    __syncthreads();
    red[tid] = lsq; __syncthreads();
    for (int s = 128; s > 0; s >>= 1) { if (tid < s) red[tid] += red[tid + s]; __syncthreads(); }
    if (tid == 0) psq[blockIdx.x] = red[0];
}

// ---------------- K7: bucket edges by dst ------------------------------------
__global__ __launch_bounds__(256) void k7_fill(
    const int* __restrict__ eidx, int* __restrict__ cnt, int* __restrict__ slot)
{
    int e = blockIdx.x * 256 + threadIdx.x;
    if (e >= N_EDGES) return;
    int dst = eidx[(size_t)e * 2 + 1];
    int pos = atomicAdd(&cnt[dst], 1);
    if (pos < MAXDEG) slot[dst * MAXDEG + pos] = e;
}

// ---------------- K8: per-node gather + norm + gelu + mean -------------------
__global__ __launch_bounds__(256) void k8_gather(
    const ushort_t* __restrict__ e0, const int* __restrict__ slot,
    const int* __restrict__ cnt, const float* __restrict__ scal,
    float* __restrict__ out)
{
    const float mu = scal[0], rs = scal[1];
    int warp = (int)((blockIdx.x * 256 + threadIdx.x) >> 6);
    int lane = threadIdx.x & 63;
    if (warp >= N_NODES) return;
    int c = cnt[warp];
    int m = min(c, MAXDEG);
    float a0 = 0.f, a1 = 0.f;
    for (int j = 0; j < m; ++j) {
        int e = slot[warp * MAXDEG + j];
        unsigned u = *(const unsigned*)&e0[(size_t)e * DD + lane * 2];
        float x0 = __uint_as_float(u << 16);
        float x1 = __uint_as_float(u & 0xffff0000u);
        a0 += gelu_f((x0 - mu) * rs);
        a1 += gelu_f((x1 - mu) * rs);
    }
    float inv = c > 0 ? 1.0f / (float)c : 0.f;
    out[(size_t)warp * DD + lane * 2] = a0 * inv;
    out[(size_t)warp * DD + lane * 2 + 1] = a1 * inv;
}

// ---------------- launch -----------------------------------------------------
extern "C" void kernel_launch(void* const* d_in, const int* in_sizes, int n_in,
                              void* d_out, int out_size, void* d_ws, size_t ws_size,
                              hipStream_t stream) {
    const float* ef  = (const float*)d_in[0];
    const float* nf  = (const float*)d_in[1];
    const int*   eix = (const int*)d_in[2];
    const float* W1  = (const float*)d_in[3];
    const float* b1  = (const float*)d_in[4];
    const float* W2  = (const float*)d_in[5];
    const float* b2  = (const float*)d_in[6];
    float* out = (float*)d_out;
    char* ws = (char*)d_ws;

    // workspace layout (bytes)
    ushort_t* hpre = (ushort_t*)(ws + 0);           // 12.8M bf16 = 25,600,000
    ushort_t* hg   = (ushort_t*)(ws + 25600000);    // 12.8M bf16 = 25,600,000
    ushort_t* e0   = (ushort_t*)(ws + 51200000);    // 81.92M bf16 = 163,840,000
    int*      cnt  = (int*)(ws + 215040000);        // 400,000
    int*      slot = (int*)(ws + 215440000);        // 25,600,000
    float*    p1s  = (float*)(ws + 241040000);      // 2048 f
    float*    p1q  = p1s + 2048;
    float*    p2s  = (float*)(ws + 241060000);      // 2560 f
    float*    p2q  = p2s + 2560;
    float*    s1   = (float*)(ws + 241090000);
    float*    s2   = (float*)(ws + 241090128);

    hipMemsetAsync(cnt, 0, N_NODES * sizeof(int), stream);
    k1_gemm1<<<1250, 256, 0, stream>>>(nf, W1, b1, hpre, p1s, p1q, 1250);
    k_reduce<<<1, 256, 0, stream>>>(p1s, p1q, 1250, (double)N_NODES * DD, s1);
    k3_act<<<6250, 256, 0, stream>>>(hpre, s1, hg);
    k4_gemm2<<<2500, 256, 0, stream>>>(ef, hg, eix, W2, b2, e0, p2s, p2q, 2500);
    k_reduce<<<1, 256, 0, stream>>>(p2s, p2q, 2500, (double)N_EDGES * DD, s2);
    k7_fill<<<2500, 256, 0, stream>>>(eix, cnt, slot);
    k8_gather<<<25000, 256, 0, stream>>>(e0, slot, cnt, s2, out);
}

// Round 3
// 286.390 us; speedup vs baseline: 1.2792x; 1.2220x over previous
//
#include <hip/hip_runtime.h>
#include <hip/hip_bf16.h>
#include <math.h>

typedef __bf16 bf16;
typedef bf16 bf16x8 __attribute__((ext_vector_type(8)));
typedef float f32x4 __attribute__((ext_vector_type(4)));
typedef unsigned short ushort_t;

#define N_NODES 100000
#define N_EDGES 640000
#define DD 128
#define MAXDEG 64

__device__ __forceinline__ float gelu_f(float x) {
    return 0.5f * x * (1.0f + erff(x * 0.70710678118654752440f));
}

// tanh-form gelu: x * sigmoid(1.59576912*(x + 0.044715 x^3)) ; |err| <~ 1e-3
__device__ __forceinline__ float gelu_fast(float x) {
    float z2 = x * (1.595769122f + 0.071354816f * x * x);
    return x * __builtin_amdgcn_rcpf(1.0f + __expf(-z2));
}

__device__ __forceinline__ ushort_t bf16_bits(float x) {
    bf16 h = (bf16)x;
    return __builtin_bit_cast(ushort_t, h);
}

__device__ __forceinline__ float bits_to_f(ushort_t u) {
    return __uint_as_float(((unsigned)u) << 16);
}

// ---------------- K1: hpre = bf16(nf @ W1 + b1) + fp32 stats partials --------
// 64-row tiles; 100000 = 1562*64 + 32 -> tail guards.
#define K1_TILES 1563
__global__ __launch_bounds__(256) void k1_gemm1(
    const float* __restrict__ nf, const float* __restrict__ W1,
    const float* __restrict__ b1, ushort_t* __restrict__ hpre,
    float* __restrict__ psum, float* __restrict__ psq, int nblocks)
{
    __shared__ bf16 Ash[64 * 136];
    __shared__ float red[256];
    const int tid = threadIdx.x;
    const int lane = tid & 63;
    const int w = tid >> 6;
    const int l15 = lane & 15, l4 = lane >> 4;

    bf16x8 bfrag[4][2];
    #pragma unroll
    for (int s = 0; s < 4; ++s)
        #pragma unroll
        for (int t = 0; t < 2; ++t) {
            int n = w * 32 + t * 16 + l15;
            #pragma unroll
            for (int j = 0; j < 8; ++j)
                bfrag[s][t][j] = (bf16)W1[(s * 32 + l4 * 8 + j) * DD + n];
        }
    float bias[2];
    bias[0] = b1[w * 32 + l15];
    bias[1] = b1[w * 32 + 16 + l15];

    float lsum = 0.f, lsq = 0.f;
    const int srow = tid >> 2;   // 0..63
    const int q = tid & 3;       // 32-col quarter

    for (int tile = blockIdx.x; tile < K1_TILES; tile += nblocks) {
        const int rbase = tile * 64;
        {
            int grow = min(rbase + srow, N_NODES - 1);
            const float4* p = (const float4*)&nf[(size_t)grow * DD + q * 32];
            #pragma unroll
            for (int u = 0; u < 4; ++u) {
                float4 a = p[2 * u], b = p[2 * u + 1];
                ushort_t o[8] = {bf16_bits(a.x), bf16_bits(a.y), bf16_bits(a.z), bf16_bits(a.w),
                                 bf16_bits(b.x), bf16_bits(b.y), bf16_bits(b.z), bf16_bits(b.w)};
                *(uint4*)&Ash[srow * 136 + q * 32 + u * 8] = *(const uint4*)o;
            }
        }
        __syncthreads();
        f32x4 acc[4][2];
        #pragma unroll
        for (int r = 0; r < 4; ++r)
            #pragma unroll
            for (int t = 0; t < 2; ++t)
                acc[r][t] = (f32x4){0.f, 0.f, 0.f, 0.f};
        #pragma unroll
        for (int s = 0; s < 4; ++s)
            #pragma unroll
            for (int r = 0; r < 4; ++r) {
                bf16x8 a = *(const bf16x8*)&Ash[(r * 16 + l15) * 136 + s * 32 + l4 * 8];
                acc[r][0] = __builtin_amdgcn_mfma_f32_16x16x32_bf16(a, bfrag[s][0], acc[r][0], 0, 0, 0);
                acc[r][1] = __builtin_amdgcn_mfma_f32_16x16x32_bf16(a, bfrag[s][1], acc[r][1], 0, 0, 0);
            }
        __syncthreads();
        #pragma unroll
        for (int r = 0; r < 4; ++r)
            #pragma unroll
            for (int t = 0; t < 2; ++t) {
                int n = w * 32 + t * 16 + l15;
                #pragma unroll
                for (int j = 0; j < 4; ++j) {
                    int rr = rbase + r * 16 + l4 * 4 + j;
                    if (rr < N_NODES) {
                        float v = acc[r][t][j] + bias[t];
                        hpre[(size_t)rr * DD + n] = bf16_bits(v);
                        lsum += v; lsq += v * v;
                    }
                }
            }
    }
    red[tid] = lsum; __syncthreads();
    for (int s = 128; s > 0; s >>= 1) { if (tid < s) red[tid] += red[tid + s]; __syncthreads(); }
    if (tid == 0) psum[blockIdx.x] = red[0];
    __syncthreads();
    red[tid] = lsq; __syncthreads();
    for (int s = 128; s > 0; s >>= 1) { if (tid < s) red[tid] += red[tid + s]; __syncthreads(); }
    if (tid == 0) psq[blockIdx.x] = red[0];
}

// ---------------- reduce partials -> mu, rsigma ------------------------------
__global__ void k_reduce(const float* __restrict__ psum, const float* __restrict__ psq,
                         int nb, double cntd, float* __restrict__ scal)
{
    __shared__ double rs_[256], rq_[256];
    int tid = threadIdx.x;
    double s = 0.0, q = 0.0;
    for (int i = tid; i < nb; i += 256) { s += psum[i]; q += psq[i]; }
    rs_[tid] = s; rq_[tid] = q; __syncthreads();
    for (int st = 128; st > 0; st >>= 1) {
        if (tid < st) { rs_[tid] += rs_[tid + st]; rq_[tid] += rq_[tid + st]; }
        __syncthreads();
    }
    if (tid == 0) {
        double mu = rs_[0] / cntd;
        double var = rq_[0] / cntd - mu * mu;
        scal[0] = (float)mu;
        scal[1] = (float)(1.0 / sqrt(var + 1e-5));
    }
}

// ---------------- K3: hg = bf16(gelu((hpre-mu)*rs)) --------------------------
__global__ __launch_bounds__(256) void k3_act(
    const ushort_t* __restrict__ hpre, const float* __restrict__ scal,
    ushort_t* __restrict__ hg)
{
    const float mu = scal[0], rs = scal[1];
    size_t i = (size_t)(blockIdx.x * 256 + threadIdx.x) * 8;
    uint4 v = *(const uint4*)(hpre + i);
    const ushort_t* in = (const ushort_t*)&v;
    ushort_t o[8];
    #pragma unroll
    for (int j = 0; j < 8; ++j)
        o[j] = bf16_bits(gelu_f((bits_to_f(in[j]) - mu) * rs));
    *(uint4*)(hg + i) = *(const uint4*)o;
}

// ---------------- K4: e0 = [ef | hg[src]] @ W2 + b2 (bf16) + stats -----------
__global__ __launch_bounds__(256) void k4_gemm2(
    const float* __restrict__ ef, const ushort_t* __restrict__ hg,
    const int* __restrict__ eidx, const float* __restrict__ W2,
    const float* __restrict__ b2, ushort_t* __restrict__ e0,
    float* __restrict__ psum, float* __restrict__ psq, int nblocks)
{
    __shared__ bf16 Ash[64 * 264];
    __shared__ float red[256];
    const int tid = threadIdx.x;
    const int lane = tid & 63;
    const int w = tid >> 6;
    const int l15 = lane & 15, l4 = lane >> 4;

    bf16x8 bfrag[8][2];
    #pragma unroll
    for (int s = 0; s < 8; ++s)
        #pragma unroll
        for (int t = 0; t < 2; ++t) {
            int n = w * 32 + t * 16 + l15;
            #pragma unroll
            for (int j = 0; j < 8; ++j)
                bfrag[s][t][j] = (bf16)W2[(s * 32 + l4 * 8 + j) * DD + n];
        }
    float bias[2];
    bias[0] = b2[w * 32 + l15];
    bias[1] = b2[w * 32 + 16 + l15];

    float lsum = 0.f, lsq = 0.f;
    const int srow = tid >> 2;
    const int q = tid & 3;

    for (int tile = blockIdx.x; tile < N_EDGES / 64; tile += nblocks) {
        const int ebase = tile * 64;
        {
            const float4* p = (const float4*)&ef[(size_t)(ebase + srow) * DD + q * 32];
            #pragma unroll
            for (int u = 0; u < 4; ++u) {
                float4 a = p[2 * u], b = p[2 * u + 1];
                ushort_t o[8] = {bf16_bits(a.x), bf16_bits(a.y), bf16_bits(a.z), bf16_bits(a.w),
                                 bf16_bits(b.x), bf16_bits(b.y), bf16_bits(b.z), bf16_bits(b.w)};
                *(uint4*)&Ash[srow * 264 + q * 32 + u * 8] = *(const uint4*)o;
            }
            int src = eidx[(size_t)(ebase + srow) * 2];
            const uint4* hp = (const uint4*)&hg[(size_t)src * DD + q * 32];
            uint4* hd = (uint4*)&Ash[srow * 264 + 128 + q * 32];
            #pragma unroll
            for (int u = 0; u < 4; ++u) hd[u] = hp[u];
        }
        __syncthreads();
        f32x4 acc[4][2];
        #pragma unroll
        for (int r = 0; r < 4; ++r)
            #pragma unroll
            for (int t = 0; t < 2; ++t)
                acc[r][t] = (f32x4){0.f, 0.f, 0.f, 0.f};
        #pragma unroll
        for (int s = 0; s < 8; ++s)
            #pragma unroll
            for (int r = 0; r < 4; ++r) {
                bf16x8 a = *(const bf16x8*)&Ash[(r * 16 + l15) * 264 + s * 32 + l4 * 8];
                acc[r][0] = __builtin_amdgcn_mfma_f32_16x16x32_bf16(a, bfrag[s][0], acc[r][0], 0, 0, 0);
                acc[r][1] = __builtin_amdgcn_mfma_f32_16x16x32_bf16(a, bfrag[s][1], acc[r][1], 0, 0, 0);
            }
        __syncthreads();
        #pragma unroll
        for (int r = 0; r < 4; ++r)
            #pragma unroll
            for (int t = 0; t < 2; ++t) {
                int n = w * 32 + t * 16 + l15;
                #pragma unroll
                for (int j = 0; j < 4; ++j) {
                    float v = acc[r][t][j] + bias[t];
                    lsum += v; lsq += v * v;
                    int rr = ebase + r * 16 + l4 * 4 + j;
                    e0[(size_t)rr * DD + n] = bf16_bits(v);
                }
            }
    }
    red[tid] = lsum; __syncthreads();
    for (int s = 128; s > 0; s >>= 1) { if (tid < s) red[tid] += red[tid + s]; __syncthreads(); }
    if (tid == 0) psum[blockIdx.x] = red[0];
    __syncthreads();
    red[tid] = lsq; __syncthreads();
    for (int s = 128; s > 0; s >>= 1) { if (tid < s) red[tid] += red[tid + s]; __syncthreads(); }
    if (tid == 0) psq[blockIdx.x] = red[0];
}

// ---------------- K7: bucket edges by dst ------------------------------------
__global__ __launch_bounds__(256) void k7_fill(
    const int* __restrict__ eidx, int* __restrict__ cnt, int* __restrict__ slot)
{
    int e = blockIdx.x * 256 + threadIdx.x;
    if (e >= N_EDGES) return;
    int dst = eidx[(size_t)e * 2 + 1];
    int pos = atomicAdd(&cnt[dst], 1);
    if (pos < MAXDEG) slot[dst * MAXDEG + pos] = e;
}

// ---------------- K8: per-node gather + norm + fast-gelu + mean --------------
// One wave per node. Slot list fetched in parallel (lane j holds entry j),
// broadcast via shfl; e0-row loads batched 4-deep for latency overlap.
__global__ __launch_bounds__(256) void k8_gather(
    const ushort_t* __restrict__ e0v, const int* __restrict__ slot,
    const int* __restrict__ cnt, const float* __restrict__ scal,
    float* __restrict__ out)
{
    const float mu = scal[0], rs = scal[1];
    int node = (int)((blockIdx.x * 256 + threadIdx.x) >> 6);
    int lane = threadIdx.x & 63;
    if (node >= N_NODES) return;
    int c = cnt[node];
    int m = min(c, MAXDEG);
    int myslot = (lane < m) ? slot[node * MAXDEG + lane] : 0;
    float a0 = 0.f, a1 = 0.f;
    const size_t off = (size_t)(lane * 2);
    int j = 0;
    for (; j + 4 <= m; j += 4) {
        int ea = __shfl(myslot, j);
        int eb = __shfl(myslot, j + 1);
        int ec = __shfl(myslot, j + 2);
        int ed = __shfl(myslot, j + 3);
        unsigned ua = *(const unsigned*)&e0v[(size_t)ea * DD + off];
        unsigned ub = *(const unsigned*)&e0v[(size_t)eb * DD + off];
        unsigned uc = *(const unsigned*)&e0v[(size_t)ec * DD + off];
        unsigned ud = *(const unsigned*)&e0v[(size_t)ed * DD + off];
        a0 += gelu_fast((__uint_as_float(ua << 16) - mu) * rs);
        a1 += gelu_fast((__uint_as_float(ua & 0xffff0000u) - mu) * rs);
        a0 += gelu_fast((__uint_as_float(ub << 16) - mu) * rs);
        a1 += gelu_fast((__uint_as_float(ub & 0xffff0000u) - mu) * rs);
        a0 += gelu_fast((__uint_as_float(uc << 16) - mu) * rs);
        a1 += gelu_fast((__uint_as_float(uc & 0xffff0000u) - mu) * rs);
        a0 += gelu_fast((__uint_as_float(ud << 16) - mu) * rs);
        a1 += gelu_fast((__uint_as_float(ud & 0xffff0000u) - mu) * rs);
    }
    for (; j < m; ++j) {
        int ea = __shfl(myslot, j);
        unsigned ua = *(const unsigned*)&e0v[(size_t)ea * DD + off];
        a0 += gelu_fast((__uint_as_float(ua << 16) - mu) * rs);
        a1 += gelu_fast((__uint_as_float(ua & 0xffff0000u) - mu) * rs);
    }
    float inv = c > 0 ? 1.0f / (float)c : 0.f;
    out[(size_t)node * DD + lane * 2] = a0 * inv;
    out[(size_t)node * DD + lane * 2 + 1] = a1 * inv;
}

// ---------------- launch -----------------------------------------------------
extern "C" void kernel_launch(void* const* d_in, const int* in_sizes, int n_in,
                              void* d_out, int out_size, void* d_ws, size_t ws_size,
                              hipStream_t stream) {
    const float* ef  = (const float*)d_in[0];
    const float* nf  = (const float*)d_in[1];
    const int*   eix = (const int*)d_in[2];
    const float* W1  = (const float*)d_in[3];
    const float* b1  = (const float*)d_in[4];
    const float* W2  = (const float*)d_in[5];
    const float* b2  = (const float*)d_in[6];
    float* out = (float*)d_out;
    char* ws = (char*)d_ws;

    ushort_t* hpre = (ushort_t*)(ws + 0);           // 25,600,000
    ushort_t* hg   = (ushort_t*)(ws + 25600000);    // 25,600,000
    ushort_t* e0   = (ushort_t*)(ws + 51200000);    // 163,840,000
    int*      cnt  = (int*)(ws + 215040000);        // 400,000
    int*      slot = (int*)(ws + 215440000);        // 25,600,000
    float*    p1s  = (float*)(ws + 241040000);
    float*    p1q  = p1s + 2048;
    float*    p2s  = (float*)(ws + 241060000);
    float*    p2q  = p2s + 2560;
    float*    s1   = (float*)(ws + 241090000);
    float*    s2   = (float*)(ws + 241090128);

    hipMemsetAsync(cnt, 0, N_NODES * sizeof(int), stream);
    k1_gemm1<<<521, 256, 0, stream>>>(nf, W1, b1, hpre, p1s, p1q, 521);
    k_reduce<<<1, 256, 0, stream>>>(p1s, p1q, 521, (double)N_NODES * DD, s1);
    k3_act<<<6250, 256, 0, stream>>>(hpre, s1, hg);
    k4_gemm2<<<2500, 256, 0, stream>>>(ef, hg, eix, W2, b2, e0, p2s, p2q, 2500);
    k_reduce<<<1, 256, 0, stream>>>(p2s, p2q, 2500, (double)N_EDGES * DD, s2);
    k7_fill<<<2500, 256, 0, stream>>>(eix, cnt, slot);
    k8_gather<<<25000, 256, 0, stream>>>(e0, slot, cnt, s2, out);
}